// Round 8
// baseline (188.283 us; speedup 1.0000x reference)
//
#include <hip/hip_runtime.h>
#include <stdint.h>

// Problem: x[B=32][N=8192][D=64] fp32 -> out[B][D][D][D] fp32 (centered 3rd moment)
// Strategy (R8): raw-moment identity. third = M3_raw - mu_d*M2[e,f] - mu_e*M2[d,f]
//  - mu_f*M2[d,e] + 2 mu_d mu_e mu_f, all moments from the SAME fp16 data.
//  -> transpose needs no mean (pure), mean kernel deleted, GEMM K-loop = R7 (proven).
#define B_SZ 32
#define N_SZ 8192
#define D_SZ 64

typedef _Float16 half8 __attribute__((ext_vector_type(8)));
typedef float f32x4 __attribute__((ext_vector_type(4)));

#define AS1 __attribute__((address_space(1)))
#define AS3 __attribute__((address_space(3)))

#define MFMA16(Aop, Bop, Cop) __builtin_amdgcn_mfma_f32_16x16x32_f16(Aop, Bop, Cop, 0, 0, 0)

// Granule layout v1 (R3/R5/R7-proven 0-conflict): per 64-n granule, chunk (d, cc)
// [8 halves, n = cc*8..+8] stored at d*64 + (cc ^ (d&7))*8 halves.

// ---------------------------------------------------------------------------
// Kernel 1: PURE raw transpose: read x fp32, cast fp16, write v1 layout.
// No mean dependency. grid = 32 b * 64 tile-pairs.
// ---------------------------------------------------------------------------
__global__ __launch_bounds__(256) void tp_transpose_kernel(const float* __restrict__ x,
                                                           _Float16* __restrict__ xcS) {
    const int b    = blockIdx.x >> 6;
    const int tp   = blockIdx.x & 63;
    const int t    = threadIdx.x;
    const int tile = tp * 2 + (t >> 7);
    const int r8   = (t >> 4) & 7;
    const int dq   = t & 15;

    const float* src = x + (size_t)b * (N_SZ * D_SZ) + (size_t)(tile * 64 + r8 * 8) * D_SZ + dq * 4;
    f32x4 v[8];
#pragma unroll
    for (int i = 0; i < 8; i++)
        v[i] = *(const f32x4*)(src + i * D_SZ);

    _Float16* dstb = xcS + (size_t)b * (N_SZ * D_SZ) + (size_t)tile * 4096;
#pragma unroll
    for (int c = 0; c < 4; c++) {
        const int d   = dq * 4 + c;
        const int ccp = r8 ^ (d & 7);
        half8 o;
#pragma unroll
        for (int i = 0; i < 8; i++)
            o[i] = (_Float16)v[i][c];
        *(half8*)(dstb + d * 64 + ccp * 8) = o;
    }
}

// ---------------------------------------------------------------------------
// Kernel 2: stats — raw S1[d] = sum_n x_d and S2[d,f] = sum_n x_d x_f (upper
// blocks) per batch, via MFMA on the fp16 data (identity-consistent).
// grid = 32 b * 8 slabs; wg = 4 waves, each staging+consuming 4 granules
// (per-wave private LDS double buffer). Cross-wave LDS reduce; wave 0 atomics.
// S1 via MFMA against all-ones B-operand (row-sums, C-layout rows = q*4+r).
// ---------------------------------------------------------------------------
__global__ __launch_bounds__(256, 2) void tp_stats_kernel(const _Float16* __restrict__ xcS,
                                                          float* __restrict__ s1,
                                                          float* __restrict__ s2) {
    const int b    = blockIdx.x >> 3;
    const int slab = blockIdx.x & 7;
    const int tid  = threadIdx.x;
    const int lane = tid & 63;
    const int wv   = tid >> 6;
    const int q    = lane >> 4;
    const int m    = lane & 15;

    __shared__ __align__(16) char lds[65536];   // 4 waves x 2 bufs x 8KB; aliased reduce

    const _Float16* gb0 = xcS + (size_t)b * (N_SZ * D_SZ)
                        + (size_t)(slab * 16 + wv * 4) * 4096 + lane * 8;

    int aOff[2][4];
#pragma unroll
    for (int ks = 0; ks < 2; ks++) {
        const int c = ks * 4 + q;
#pragma unroll
        for (int i = 0; i < 4; i++) {
            const int r = i * 16 + m;
            aOff[ks][i] = r * 128 + ((c ^ (r & 7)) * 16);
        }
    }

    f32x4 accM[10], accS[4];
#pragma unroll
    for (int k = 0; k < 10; k++) accM[k] = (f32x4){0.f, 0.f, 0.f, 0.f};
#pragma unroll
    for (int i = 0; i < 4; i++) accS[i] = (f32x4){0.f, 0.f, 0.f, 0.f};
    half8 ones;
#pragma unroll
    for (int i = 0; i < 8; i++) ones[i] = (_Float16)1.0f;

    auto stage = [&](int t, int bi) {
        char* lb = lds + wv * 16384 + bi * 8192;
        const _Float16* gb = gb0 + (size_t)t * 4096;
#pragma unroll
        for (int k = 0; k < 8; k++)
            __builtin_amdgcn_global_load_lds((const AS1 void*)(gb + k * 512),
                                             (AS3 void*)(lb + k * 1024), 16, 0, 0);
    };

    stage(0, 0);
    for (int t = 0; t < 4; t++) {
        __syncthreads();
        if (t < 3) stage(t + 1, (t + 1) & 1);
        const char* tb = lds + wv * 16384 + (t & 1) * 8192;
#pragma unroll
        for (int ks = 0; ks < 2; ks++) {
            half8 A0 = *(const half8*)(tb + aOff[ks][0]);
            half8 A1 = *(const half8*)(tb + aOff[ks][1]);
            half8 A2 = *(const half8*)(tb + aOff[ks][2]);
            half8 A3 = *(const half8*)(tb + aOff[ks][3]);
            accM[0] = MFMA16(A0, A0, accM[0]);
            accM[1] = MFMA16(A0, A1, accM[1]);
            accM[2] = MFMA16(A0, A2, accM[2]);
            accM[3] = MFMA16(A0, A3, accM[3]);
            accM[4] = MFMA16(A1, A1, accM[4]);
            accM[5] = MFMA16(A1, A2, accM[5]);
            accM[6] = MFMA16(A1, A3, accM[6]);
            accM[7] = MFMA16(A2, A2, accM[7]);
            accM[8] = MFMA16(A2, A3, accM[8]);
            accM[9] = MFMA16(A3, A3, accM[9]);
            accS[0] = MFMA16(A0, ones, accS[0]);
            accS[1] = MFMA16(A1, ones, accS[1]);
            accS[2] = MFMA16(A2, ones, accS[2]);
            accS[3] = MFMA16(A3, ones, accS[3]);
        }
    }
    __syncthreads();

    float* redL = (float*)lds;
    if (wv != 0) {
        float* w = redL + (wv - 1) * 3584 + lane * 4;
#pragma unroll
        for (int k = 0; k < 10; k++) *(f32x4*)(w + k * 256) = accM[k];
#pragma unroll
        for (int i = 0; i < 4; i++)  *(f32x4*)(w + (10 + i) * 256) = accS[i];
    }
    __syncthreads();
    if (wv == 0) {
#pragma unroll
        for (int u = 0; u < 3; u++) {
            const float* rr = redL + u * 3584 + lane * 4;
#pragma unroll
            for (int k = 0; k < 10; k++) accM[k] += *(const f32x4*)(rr + k * 256);
#pragma unroll
            for (int i = 0; i < 4; i++)  accS[i] += *(const f32x4*)(rr + (10 + i) * 256);
        }
        float* s2b = s2 + b * 4096;
        int idx = 0;
#pragma unroll
        for (int i = 0; i < 4; i++) {
#pragma unroll
            for (int j = i; j < 4; j++, idx++) {
#pragma unroll
                for (int r = 0; r < 4; r++)
                    atomicAdd(&s2b[(16 * i + q * 4 + r) * 64 + 16 * j + m], accM[idx][r]);
            }
        }
        if (m == 0) {
#pragma unroll
            for (int i = 0; i < 4; i++)
#pragma unroll
                for (int r = 0; r < 4; r++)
                    atomicAdd(&s1[b * 64 + 16 * i + q * 4 + r], accS[i][r]);
        }
    }
}

// ---------------------------------------------------------------------------
// Kernel 3: symmetric batched GEMM on RAW fp16 (K-loop identical to R7) +
// identity correction in the fp32 epilogue from S1/S2 tables (L1-resident).
// ---------------------------------------------------------------------------
__global__ __launch_bounds__(256, 2) void tp_gemm_kernel(const _Float16* __restrict__ xcS,
                                                         const float* __restrict__ s1,
                                                         const float* __restrict__ s2,
                                                         float* __restrict__ out) {
    const int b    = blockIdx.x;          // 0..31
    const int eg   = blockIdx.y;          // 0..15
    const int tid  = threadIdx.x;
    const int lane = tid & 63;
    const int wv   = tid >> 6;            // 0..3
    const int h    = wv & 1;              // N-half
    const int p    = wv >> 1;             // e-pair within quad
    const int q    = lane >> 4;           // 0..3
    const int m    = lane & 15;
    const int e0   = eg * 4 + p * 2;

    __shared__ __align__(16) char ldsraw[65536];
    float* redL = (float*)ldsraw;

    const _Float16* gbase = xcS + (size_t)b * (N_SZ * D_SZ)
                          + (size_t)h * (N_SZ / 2) * D_SZ
                          + (size_t)(p * 2048 + lane * 8);

    int aOff[2][4], sOff[2][2];
#pragma unroll
    for (int ks = 0; ks < 2; ks++) {
        const int c = ks * 4 + q;
#pragma unroll
        for (int i = 0; i < 4; i++) {
            const int r = i * 16 + m;
            aOff[ks][i] = r * 128 + ((c ^ (r & 7)) * 16);
        }
#pragma unroll
        for (int j = 0; j < 2; j++) {
            const int e = e0 + j;
            sOff[ks][j] = e * 128 + ((c ^ (e & 7)) * 16);
        }
    }

    f32x4 acc[2][10];
#pragma unroll
    for (int ej = 0; ej < 2; ej++)
#pragma unroll
        for (int k = 0; k < 10; k++)
            acc[ej][k] = (f32x4){0.f, 0.f, 0.f, 0.f};

    auto stage = [&](int T, int bi) {
        _Float16* lb = (_Float16*)(ldsraw + bi * 32768 + h * 16384 + p * 4096);
        const _Float16* gb = gbase + (size_t)T * 8192;
#pragma unroll
        for (int g = 0; g < 2; g++)
#pragma unroll
            for (int k = 0; k < 4; k++)
                __builtin_amdgcn_global_load_lds(
                    (const AS1 void*)(gb + g * 4096 + k * 512),
                    (AS3 void*)(lb + g * 4096 + k * 512), 16, 0, 0);
    };

    stage(0, 0);

    for (int T = 0; T < 32; T++) {
        __syncthreads();
        if (T < 31) stage(T + 1, (T + 1) & 1);
        const char* hb = ldsraw + (T & 1) * 32768 + h * 16384;
#pragma unroll
        for (int g = 0; g < 2; g++) {
            const char* tb = hb + g * 8192;
#pragma unroll
            for (int ks = 0; ks < 2; ks++) {
                half8 A0 = *(const half8*)(tb + aOff[ks][0]);
                half8 A1 = *(const half8*)(tb + aOff[ks][1]);
                half8 A2 = *(const half8*)(tb + aOff[ks][2]);
                half8 A3 = *(const half8*)(tb + aOff[ks][3]);
                half8 S0 = *(const half8*)(tb + sOff[ks][0]);
                half8 S1v = *(const half8*)(tb + sOff[ks][1]);
#pragma unroll
                for (int ej = 0; ej < 2; ej++) {
                    half8 S = ej ? S1v : S0;
                    half8 P0 = A0 * S;
                    half8 P1 = A1 * S;
                    half8 P2 = A2 * S;
                    half8 P3 = A3 * S;
                    acc[ej][0] = MFMA16(P0, A0, acc[ej][0]);
                    acc[ej][1] = MFMA16(P0, A1, acc[ej][1]);
                    acc[ej][2] = MFMA16(P0, A2, acc[ej][2]);
                    acc[ej][3] = MFMA16(P0, A3, acc[ej][3]);
                    acc[ej][4] = MFMA16(P1, A1, acc[ej][4]);
                    acc[ej][5] = MFMA16(P1, A2, acc[ej][5]);
                    acc[ej][6] = MFMA16(P1, A3, acc[ej][6]);
                    acc[ej][7] = MFMA16(P2, A2, acc[ej][7]);
                    acc[ej][8] = MFMA16(P2, A3, acc[ej][8]);
                    acc[ej][9] = MFMA16(P3, A3, acc[ej][9]);
                }
            }
        }
    }
    __syncthreads();

    // cross-h reduction (R4-proven)
    const int rbase = p * 5120 + lane * 4;
    if (h == 1) {
#pragma unroll
        for (int ej = 0; ej < 2; ej++)
#pragma unroll
            for (int k = 0; k < 10; k++)
                *(f32x4*)(redL + rbase + (ej * 10 + k) * 256) = acc[ej][k];
    }
    __syncthreads();
    if (h == 0) {
#pragma unroll
        for (int ej = 0; ej < 2; ej++)
#pragma unroll
            for (int k = 0; k < 10; k++)
                acc[ej][k] += *(const f32x4*)(redL + rbase + (ej * 10 + k) * 256);

        const float invn = 1.0f / (float)N_SZ;
        const float* s1b = s1 + b * 64;
        const float* s2b = s2 + b * 4096;
        float* outb = out + (size_t)b * (D_SZ * D_SZ * D_SZ);
#pragma unroll
        for (int ej = 0; ej < 2; ej++) {
            const int e = e0 + ej;
            const float mu_e = s1b[e] * invn;
            int idx = 0;
#pragma unroll
            for (int i = 0; i < 4; i++) {
                const int dbase = 16 * i + q * 4;
                f32x4 mud = *(const f32x4*)(s1b + dbase) * invn;
                float s2de[4];
#pragma unroll
                for (int r = 0; r < 4; r++) {
                    const int d = dbase + r;
                    const int a = d < e ? d : e, c = d < e ? e : d;
                    s2de[r] = s2b[a * 64 + c];
                }
#pragma unroll
                for (int j = i; j < 4; j++, idx++) {
                    const int f = 16 * j + m;
                    const float muf = s1b[f] * invn;
                    const int ae = e < f ? e : f, ce = e < f ? f : e;
                    const float s2ef = s2b[ae * 64 + ce];
                    f32x4 res;
#pragma unroll
                    for (int r = 0; r < 4; r++) {
                        const int d = dbase + r;
                        const int a = d < f ? d : f, c = d < f ? f : d;
                        const float s2df = s2b[a * 64 + c];
                        res[r] = (acc[ej][idx][r] - mud[r] * s2ef - mu_e * s2df
                                  - muf * s2de[r]) * invn
                                 + 2.0f * mud[r] * mu_e * muf;
                    }
#pragma unroll
                    for (int r = 0; r < 4; r++)
                        outb[(size_t)(dbase + r) * 4096 + e * 64 + f] = res[r];
                    if (i != j)
                        *(f32x4*)&outb[(size_t)f * 4096 + e * 64 + dbase] = res;
                }
            }
        }
    }
}

// ---------------------------------------------------------------------------
extern "C" void kernel_launch(void* const* d_in, const int* in_sizes, int n_in,
                              void* d_out, int out_size, void* d_ws, size_t ws_size,
                              hipStream_t stream) {
    const float* x = (const float*)d_in[0];
    float* out = (float*)d_out;

    // ws layout: [0,8K) S1 fp32; [8K, 8K+512K) S2 fp32; xcS fp16 after.
    float* s1 = (float*)d_ws;
    float* s2 = (float*)((char*)d_ws + 8192);
    _Float16* xcS = (_Float16*)((char*)d_ws + 532480);

    hipMemsetAsync(d_ws, 0, 532480, stream);
    tp_transpose_kernel<<<dim3(B_SZ * 64), 256, 0, stream>>>(x, xcS);
    tp_stats_kernel<<<dim3(B_SZ * 8), 256, 0, stream>>>(xcS, s1, s2);
    tp_gemm_kernel<<<dim3(32, 16), 256, 0, stream>>>(xcS, s1, s2, out);
}